// Round 2
// baseline (1128.960 us; speedup 1.0000x reference)
//
#include <hip/hip_runtime.h>

typedef unsigned short ushort_t;
typedef __attribute__((ext_vector_type(8))) short short8;
typedef __attribute__((ext_vector_type(4))) float f32x4;

#define BT 4096
#define TSEQ 2048
#define CC 1024
#define NH 16
#define DH 64
#define HID 4096
#define ATT_SCALE 0.03125f   /* C^-0.5 = 1/32 (reference scales by C, not DH) */

__device__ __forceinline__ ushort_t f2bf(float f) {
    unsigned u = __float_as_uint(f);
    u = u + 0x7fffu + ((u >> 16) & 1u);
    return (ushort_t)(u >> 16);
}
__device__ __forceinline__ float bf2f(ushort_t u) {
    return __uint_as_float(((unsigned)u) << 16);
}

// ---------------------------------------------------------------------------
// Tiled transpose + f32->bf16 convert:  in [R][Cn] f32  ->  out [Cn][R] bf16
// grid: (Cn/32, R/32, batch), block 256
// ---------------------------------------------------------------------------
__global__ __launch_bounds__(256) void transpose_cvt(
    const float* __restrict__ in, ushort_t* __restrict__ out, int R, int Cn)
{
    __shared__ float tile[32][33];
    size_t off = (size_t)blockIdx.z * R * Cn;
    int c0 = blockIdx.x * 32, r0 = blockIdx.y * 32;
    int tx = threadIdx.x & 31, ty = threadIdx.x >> 5;  // ty in 0..7
#pragma unroll
    for (int q = 0; q < 4; ++q)
        tile[ty + 8 * q][tx] = in[off + (size_t)(r0 + ty + 8 * q) * Cn + c0 + tx];
    __syncthreads();
#pragma unroll
    for (int q = 0; q < 4; ++q)
        out[off + (size_t)(c0 + ty + 8 * q) * R + r0 + tx] = f2bf(tile[tx][ty + 8 * q]);
}

// ---------------------------------------------------------------------------
// LayerNorm row kernel: x f32 [rows][1024] -> out bf16.  grid rows, block 256.
// ---------------------------------------------------------------------------
__global__ __launch_bounds__(256) void ln_kernel(
    const float* __restrict__ x, const float* __restrict__ g,
    const float* __restrict__ b, ushort_t* __restrict__ out)
{
    int row = blockIdx.x;
    const float4 xv = ((const float4*)(x + (size_t)row * CC))[threadIdx.x];
    float s = xv.x + xv.y + xv.z + xv.w;
    float s2 = xv.x * xv.x + xv.y * xv.y + xv.z * xv.z + xv.w * xv.w;
#pragma unroll
    for (int d = 1; d < 64; d <<= 1) {
        s += __shfl_xor(s, d);
        s2 += __shfl_xor(s2, d);
    }
    __shared__ float ps[4], ps2[4];
    int w = threadIdx.x >> 6, lane = threadIdx.x & 63;
    if (lane == 0) { ps[w] = s; ps2[w] = s2; }
    __syncthreads();
    s = ps[0] + ps[1] + ps[2] + ps[3];
    s2 = ps2[0] + ps2[1] + ps2[2] + ps2[3];
    float mu = s * (1.0f / CC);
    float var = s2 * (1.0f / CC) - mu * mu;
    float rs = rsqrtf(var + 1e-5f);
    int c = threadIdx.x * 4;
    const float4 gv = ((const float4*)g)[threadIdx.x];
    const float4 bv = ((const float4*)b)[threadIdx.x];
    ushort_t u0 = f2bf((xv.x - mu) * rs * gv.x + bv.x);
    ushort_t u1 = f2bf((xv.y - mu) * rs * gv.y + bv.y);
    ushort_t u2 = f2bf((xv.z - mu) * rs * gv.z + bv.z);
    ushort_t u3 = f2bf((xv.w - mu) * rs * gv.w + bv.w);
    unsigned lo = (unsigned)u0 | ((unsigned)u1 << 16);
    unsigned hi = (unsigned)u2 | ((unsigned)u3 << 16);
    ((uint2*)(out + (size_t)row * CC + c))[0] = make_uint2(lo, hi);
}

// ---------------------------------------------------------------------------
// QKV GEMM: h[4096][1024] bf16  x  W^T[head][64][1024] bf16 -> Q/K bf16
// [bh][t][64], V transposed -> Vt [bh][64][2048].
// grid (64, 16, 3)  block 256 (4 waves, each 16 rows x 64 cols)
// ---------------------------------------------------------------------------
__global__ __launch_bounds__(256) void qkv_gemm(
    const ushort_t* __restrict__ h, const ushort_t* __restrict__ WqT,
    const ushort_t* __restrict__ WkT, const ushort_t* __restrict__ WvT,
    ushort_t* __restrict__ Q, ushort_t* __restrict__ Kb, ushort_t* __restrict__ Vt)
{
    int w = threadIdx.x >> 6, lane = threadIdx.x & 63;
    int g = lane >> 4, c = lane & 15;
    int m0 = blockIdx.x * 64 + w * 16;
    int head = blockIdx.y;
    int mat = blockIdx.z;
    const ushort_t* Wt = (mat == 0 ? WqT : (mat == 1 ? WkT : WvT)) + (size_t)head * DH * CC;
    const ushort_t* ap = h + (size_t)(m0 + c) * CC + g * 8;
    const ushort_t* bp = Wt + (size_t)c * CC + g * 8;
    f32x4 acc[4];
#pragma unroll
    for (int nf = 0; nf < 4; ++nf) acc[nf] = f32x4{0.f, 0.f, 0.f, 0.f};
    for (int k = 0; k < CC; k += 32) {
        short8 a = *(const short8*)(ap + k);
#pragma unroll
        for (int nf = 0; nf < 4; ++nf) {
            short8 bb = *(const short8*)(bp + (size_t)nf * 16 * CC + k);
            acc[nf] = __builtin_amdgcn_mfma_f32_16x16x32_bf16(a, bb, acc[nf], 0, 0, 0);
        }
    }
#pragma unroll
    for (int nf = 0; nf < 4; ++nf)
#pragma unroll
        for (int i = 0; i < 4; ++i) {
            int m = m0 + g * 4 + i;
            int d = nf * 16 + c;
            int bb = m >> 11, t = m & (TSEQ - 1);
            int bh = bb * NH + head;
            ushort_t val = f2bf(acc[nf][i]);
            if (mat == 0)      Q[((size_t)bh * TSEQ + t) * DH + d] = val;
            else if (mat == 1) Kb[((size_t)bh * TSEQ + t) * DH + d] = val;
            else               Vt[((size_t)bh * DH + d) * TSEQ + t] = val;
        }
}

// ---------------------------------------------------------------------------
// Flash attention: per-wave 16 q-rows, s-tiles of 32, online softmax.
// grid (T/64=32, B*H=32), block 256.
// ---------------------------------------------------------------------------
__global__ __launch_bounds__(256) void flash_attn(
    const ushort_t* __restrict__ Q, const ushort_t* __restrict__ Kb,
    const ushort_t* __restrict__ Vt, ushort_t* __restrict__ attout)
{
    __shared__ ushort_t Plds[4][16][32];
    int w = threadIdx.x >> 6, lane = threadIdx.x & 63;
    int g = lane >> 4, c = lane & 15;
    int bh = blockIdx.y;
    int bb = bh >> 4, hh = bh & 15;
    int q0 = blockIdx.x * 64 + w * 16;
    const ushort_t* qp = Q + (size_t)bh * TSEQ * DH;
    const ushort_t* kp = Kb + (size_t)bh * TSEQ * DH;
    const ushort_t* vp = Vt + (size_t)bh * DH * TSEQ;

    short8 aq0 = *(const short8*)(qp + (size_t)(q0 + c) * DH + g * 8);
    short8 aq1 = *(const short8*)(qp + (size_t)(q0 + c) * DH + 32 + g * 8);

    float m_[4], l_[4];
    f32x4 o[4];
#pragma unroll
    for (int i = 0; i < 4; ++i) { m_[i] = -INFINITY; l_[i] = 0.f; }
#pragma unroll
    for (int nf = 0; nf < 4; ++nf) o[nf] = f32x4{0.f, 0.f, 0.f, 0.f};

    int nst = (q0 + 15) / 32 + 1;
    for (int st = 0; st < nst; ++st) {
        int s0 = st * 32;
        f32x4 sa[2];
#pragma unroll
        for (int sub = 0; sub < 2; ++sub) {
            short8 b0 = *(const short8*)(kp + (size_t)(s0 + sub * 16 + c) * DH + g * 8);
            short8 b1 = *(const short8*)(kp + (size_t)(s0 + sub * 16 + c) * DH + 32 + g * 8);
            f32x4 t = f32x4{0.f, 0.f, 0.f, 0.f};
            t = __builtin_amdgcn_mfma_f32_16x16x32_bf16(aq0, b0, t, 0, 0, 0);
            t = __builtin_amdgcn_mfma_f32_16x16x32_bf16(aq1, b1, t, 0, 0, 0);
            sa[sub] = t;
        }
        float p0s[4], p1s[4];
#pragma unroll
        for (int i = 0; i < 4; ++i) {
            int tg = q0 + g * 4 + i;
            float v0 = sa[0][i] * ATT_SCALE;
            float v1 = sa[1][i] * ATT_SCALE;
            if (s0 + c > tg) v0 = -INFINITY;
            if (s0 + 16 + c > tg) v1 = -INFINITY;
            float tmax = fmaxf(v0, v1);
#pragma unroll
            for (int d = 1; d < 16; d <<= 1) tmax = fmaxf(tmax, __shfl_xor(tmax, d));
            float mn = fmaxf(m_[i], tmax);
            float fac = expf(m_[i] - mn);
            float p0 = expf(v0 - mn), p1 = expf(v1 - mn);
            float rs = p0 + p1;
#pragma unroll
            for (int d = 1; d < 16; d <<= 1) rs += __shfl_xor(rs, d);
            l_[i] = l_[i] * fac + rs;
            m_[i] = mn;
            p0s[i] = p0; p1s[i] = p1;
#pragma unroll
            for (int nf = 0; nf < 4; ++nf) o[nf][i] *= fac;
        }
        // transpose P through per-wave LDS into A-fragment layout
#pragma unroll
        for (int i = 0; i < 4; ++i) {
            Plds[w][g * 4 + i][c] = f2bf(p0s[i]);
            Plds[w][g * 4 + i][16 + c] = f2bf(p1s[i]);
        }
        asm volatile("s_waitcnt lgkmcnt(0)" ::: "memory");
        short8 pa = *(const short8*)(&Plds[w][c][g * 8]);
#pragma unroll
        for (int nf = 0; nf < 4; ++nf) {
            short8 vb = *(const short8*)(vp + (size_t)(nf * 16 + c) * TSEQ + s0 + g * 8);
            o[nf] = __builtin_amdgcn_mfma_f32_16x16x32_bf16(pa, vb, o[nf], 0, 0, 0);
        }
    }
#pragma unroll
    for (int nf = 0; nf < 4; ++nf)
#pragma unroll
        for (int i = 0; i < 4; ++i) {
            int t = q0 + g * 4 + i;
            float v = o[nf][i] / l_[i];
            attout[((size_t)(bb * TSEQ + t)) * CC + hh * DH + nf * 16 + c] = f2bf(v);
        }
}

// ---------------------------------------------------------------------------
// Generic NT GEMM, 64x64 block tile, 4 waves x (16x64).
// MODE 0:  out f32 = acc + bias[n] + resid[m][n]
// MODE 1:  out bf16 = relu(acc + bias[n])
// ---------------------------------------------------------------------------
template <int MODE>
__global__ __launch_bounds__(256) void gemm_nt(
    const ushort_t* __restrict__ A, const ushort_t* __restrict__ Bt,
    int N, int K,
    const float* __restrict__ bias, const float* __restrict__ resid,
    void* __restrict__ out)
{
    int w = threadIdx.x >> 6, lane = threadIdx.x & 63;
    int g = lane >> 4, c = lane & 15;
    int m0 = blockIdx.x * 64 + w * 16;
    int n0 = blockIdx.y * 64;
    const ushort_t* ap = A + (size_t)(m0 + c) * K + g * 8;
    const ushort_t* bp = Bt + (size_t)(n0 + c) * K + g * 8;
    f32x4 acc[4];
#pragma unroll
    for (int nf = 0; nf < 4; ++nf) acc[nf] = f32x4{0.f, 0.f, 0.f, 0.f};
    for (int k = 0; k < K; k += 32) {
        short8 a = *(const short8*)(ap + k);
#pragma unroll
        for (int nf = 0; nf < 4; ++nf) {
            short8 bb = *(const short8*)(bp + (size_t)nf * 16 * K + k);
            acc[nf] = __builtin_amdgcn_mfma_f32_16x16x32_bf16(a, bb, acc[nf], 0, 0, 0);
        }
    }
#pragma unroll
    for (int nf = 0; nf < 4; ++nf)
#pragma unroll
        for (int i = 0; i < 4; ++i) {
            int m = m0 + g * 4 + i;
            int n = n0 + nf * 16 + c;
            float v = acc[nf][i];
            if (MODE == 0) {
                v += bias[n] + resid[(size_t)m * N + n];
                ((float*)out)[(size_t)m * N + n] = v;
            } else {
                v += bias[n];
                v = v > 0.f ? v : 0.f;
                ((ushort_t*)out)[(size_t)m * N + n] = f2bf(v);
            }
        }
}

// ---------------------------------------------------------------------------
extern "C" void kernel_launch(void* const* d_in, const int* in_sizes, int n_in,
                              void* d_out, int out_size, void* d_ws, size_t ws_size,
                              hipStream_t stream)
{
    (void)in_sizes; (void)n_in; (void)out_size; (void)ws_size;
    const float* x     = (const float*)d_in[0];
    const float* ln1_g = (const float*)d_in[1];
    const float* ln1_b = (const float*)d_in[2];
    const float* Wq    = (const float*)d_in[3];
    const float* Wk    = (const float*)d_in[4];
    const float* Wv    = (const float*)d_in[5];
    const float* Wo    = (const float*)d_in[6];
    const float* bo    = (const float*)d_in[7];
    const float* ln2_g = (const float*)d_in[8];
    const float* ln2_b = (const float*)d_in[9];
    const float* W1    = (const float*)d_in[10];
    const float* b1    = (const float*)d_in[11];
    const float* W2    = (const float*)d_in[12];
    const float* b2    = (const float*)d_in[13];

    char* p = (char*)d_ws;
    ushort_t* hbuf = (ushort_t*)p;  p += (size_t)BT * CC * 2;         // 8 MB
    ushort_t* WqT  = (ushort_t*)p;  p += (size_t)NH * CC * DH * 2;    // 2 MB
    ushort_t* WkT  = (ushort_t*)p;  p += (size_t)NH * CC * DH * 2;    // 2 MB
    ushort_t* WvT  = (ushort_t*)p;  p += (size_t)NH * CC * DH * 2;    // 2 MB
    ushort_t* WoT  = (ushort_t*)p;  p += (size_t)CC * CC * 2;         // 2 MB
    ushort_t* W1T  = (ushort_t*)p;  p += (size_t)CC * HID * 2;        // 8 MB
    ushort_t* W2T  = (ushort_t*)p;  p += (size_t)HID * CC * 2;        // 8 MB
    ushort_t* Qb   = (ushort_t*)p;  p += (size_t)BT * CC * 2;         // 8 MB
    ushort_t* Kbuf = (ushort_t*)p;  p += (size_t)BT * CC * 2;         // 8 MB
    ushort_t* Vt   = (ushort_t*)p;  p += (size_t)BT * CC * 2;         // 8 MB
    ushort_t* atto = (ushort_t*)p;  p += (size_t)BT * CC * 2;         // 8 MB
    float*    x1   = (float*)p;     p += (size_t)BT * CC * 4;         // 16 MB
    ushort_t* h2   = (ushort_t*)p;  p += (size_t)BT * CC * 2;         // 8 MB
    ushort_t* mid  = (ushort_t*)p;  p += (size_t)BT * HID * 2;        // 32 MB

    dim3 blk(256);
    // weight transposes (f32 -> bf16, [R][C] -> [C][R])
    transpose_cvt<<<dim3(DH / 32, CC / 32, NH), blk, 0, stream>>>(Wq, WqT, CC, DH);
    transpose_cvt<<<dim3(DH / 32, CC / 32, NH), blk, 0, stream>>>(Wk, WkT, CC, DH);
    transpose_cvt<<<dim3(DH / 32, CC / 32, NH), blk, 0, stream>>>(Wv, WvT, CC, DH);
    transpose_cvt<<<dim3(CC / 32, CC / 32, 1), blk, 0, stream>>>(Wo, WoT, CC, CC);
    transpose_cvt<<<dim3(HID / 32, CC / 32, 1), blk, 0, stream>>>(W1, W1T, CC, HID);
    transpose_cvt<<<dim3(CC / 32, HID / 32, 1), blk, 0, stream>>>(W2, W2T, HID, CC);

    // LN1
    ln_kernel<<<dim3(BT), blk, 0, stream>>>(x, ln1_g, ln1_b, hbuf);
    // QKV
    qkv_gemm<<<dim3(BT / 64, NH, 3), blk, 0, stream>>>(hbuf, WqT, WkT, WvT, Qb, Kbuf, Vt);
    // flash attention
    flash_attn<<<dim3(TSEQ / 64, 2 * NH), blk, 0, stream>>>(Qb, Kbuf, Vt, atto);
    // out projection + residual -> x1 (f32)
    gemm_nt<0><<<dim3(BT / 64, CC / 64), blk, 0, stream>>>(atto, WoT, CC, CC, bo, x, (void*)x1);
    // LN2
    ln_kernel<<<dim3(BT), blk, 0, stream>>>(x1, ln2_g, ln2_b, h2);
    // FFN1: relu(h2 @ W1 + b1) -> mid (bf16)
    gemm_nt<1><<<dim3(BT / 64, HID / 64), blk, 0, stream>>>(h2, W1T, HID, CC, b1, nullptr, (void*)mid);
    // FFN2: x1 + mid @ W2 + b2 -> d_out (f32)
    gemm_nt<0><<<dim3(BT / 64, CC / 64), blk, 0, stream>>>(mid, W2T, CC, HID, b2, x1, d_out);
}

// Round 3
// 457.364 us; speedup vs baseline: 2.4684x; 2.4684x over previous
//
#include <hip/hip_runtime.h>

typedef unsigned short ushort_t;
typedef __attribute__((ext_vector_type(8))) short short8;
typedef __attribute__((ext_vector_type(4))) float f32x4;

#define BT 4096
#define TSEQ 2048
#define CC 1024
#define NH 16
#define DH 64
#define HID 4096
#define ATT_SCALE 0.03125f   /* C^-0.5 = 1/32 (reference scales by C, not DH) */

__device__ __forceinline__ ushort_t f2bf(float f) {
    unsigned u = __float_as_uint(f);
    u = u + 0x7fffu + ((u >> 16) & 1u);
    return (ushort_t)(u >> 16);
}

typedef const __attribute__((address_space(1))) unsigned int* gptr_t;
typedef __attribute__((address_space(3))) unsigned int* lptr_t;
__device__ __forceinline__ void gload_lds16(const void* g, void* l) {
    __builtin_amdgcn_global_load_lds((gptr_t)g, (lptr_t)l, 16, 0, 0);
}

// ---------------------------------------------------------------------------
// Tiled transpose + f32->bf16 convert:  in [R][Cn] f32  ->  out [Cn][R] bf16
// ---------------------------------------------------------------------------
__global__ __launch_bounds__(256) void transpose_cvt(
    const float* __restrict__ in, ushort_t* __restrict__ out, int R, int Cn)
{
    __shared__ float tile[32][33];
    size_t off = (size_t)blockIdx.z * R * Cn;
    int c0 = blockIdx.x * 32, r0 = blockIdx.y * 32;
    int tx = threadIdx.x & 31, ty = threadIdx.x >> 5;
#pragma unroll
    for (int q = 0; q < 4; ++q)
        tile[ty + 8 * q][tx] = in[off + (size_t)(r0 + ty + 8 * q) * Cn + c0 + tx];
    __syncthreads();
#pragma unroll
    for (int q = 0; q < 4; ++q)
        out[off + (size_t)(c0 + ty + 8 * q) * R + r0 + tx] = f2bf(tile[tx][ty + 8 * q]);
}

// ---------------------------------------------------------------------------
// LayerNorm row kernel: x f32 [rows][1024] -> out bf16.
// ---------------------------------------------------------------------------
__global__ __launch_bounds__(256) void ln_kernel(
    const float* __restrict__ x, const float* __restrict__ g,
    const float* __restrict__ b, ushort_t* __restrict__ out)
{
    int row = blockIdx.x;
    const float4 xv = ((const float4*)(x + (size_t)row * CC))[threadIdx.x];
    float s = xv.x + xv.y + xv.z + xv.w;
    float s2 = xv.x * xv.x + xv.y * xv.y + xv.z * xv.z + xv.w * xv.w;
#pragma unroll
    for (int d = 1; d < 64; d <<= 1) {
        s += __shfl_xor(s, d);
        s2 += __shfl_xor(s2, d);
    }
    __shared__ float ps[4], ps2[4];
    int w = threadIdx.x >> 6, lane = threadIdx.x & 63;
    if (lane == 0) { ps[w] = s; ps2[w] = s2; }
    __syncthreads();
    s = ps[0] + ps[1] + ps[2] + ps[3];
    s2 = ps2[0] + ps2[1] + ps2[2] + ps2[3];
    float mu = s * (1.0f / CC);
    float var = s2 * (1.0f / CC) - mu * mu;
    float rs = rsqrtf(var + 1e-5f);
    int c = threadIdx.x * 4;
    const float4 gv = ((const float4*)g)[threadIdx.x];
    const float4 bv = ((const float4*)b)[threadIdx.x];
    ushort_t u0 = f2bf((xv.x - mu) * rs * gv.x + bv.x);
    ushort_t u1 = f2bf((xv.y - mu) * rs * gv.y + bv.y);
    ushort_t u2 = f2bf((xv.z - mu) * rs * gv.z + bv.z);
    ushort_t u3 = f2bf((xv.w - mu) * rs * gv.w + bv.w);
    unsigned lo = (unsigned)u0 | ((unsigned)u1 << 16);
    unsigned hi = (unsigned)u2 | ((unsigned)u3 << 16);
    ((uint2*)(out + (size_t)row * CC + c))[0] = make_uint2(lo, hi);
}

// ---------------------------------------------------------------------------
// LDS-staged NT GEMM (m97 structure): BMxBN tile, BK=32, 256 threads.
// A [M][K] bf16 row-major, Bt [N][K] bf16 (i.e. B^T).  global_load_lds w=16.
// Wave grid WM x WN, per-wave fragments MR x NR of 16x16.
// MODE 0: f32 out = acc + bias[n] + resid[m][n]
// MODE 1: bf16 out = relu(acc + bias[n])
// MODE 2: QKV scatter: n<1024 -> Q[bh][t][d], <2048 -> K, else V^T[bh][d][t]
// ---------------------------------------------------------------------------
template <int BM, int BN, int WM, int WN, int MR, int NR, int MODE>
__global__ __launch_bounds__(256) void gemm_tile(
    const ushort_t* __restrict__ A, const ushort_t* __restrict__ Bt,
    int N, int K,
    const float* __restrict__ bias, const float* __restrict__ resid,
    void* __restrict__ out0, void* __restrict__ out1, void* __restrict__ out2)
{
    static_assert(WM * WN == 4 && WM * MR * 16 == BM && WN * NR * 16 == BN, "geom");
    __shared__ ushort_t As[BM * 32];
    __shared__ ushort_t Bs[BN * 32];

    const int t = threadIdx.x;
    const int w = t >> 6, lane = t & 63, g = lane >> 4, c = lane & 15;
    const int wr = w / WN, wc = w % WN;
    const int m0 = blockIdx.x * BM;
    const int n0 = blockIdx.y * BN;

    f32x4 acc[MR][NR];
#pragma unroll
    for (int mi = 0; mi < MR; ++mi)
#pragma unroll
        for (int ni = 0; ni < NR; ++ni) acc[mi][ni] = f32x4{0.f, 0.f, 0.f, 0.f};

    // LDS read bases (byte-exact element offsets): row stride 32 elems
    const ushort_t* Ard = As + (size_t)(wr * MR * 16 + c) * 32 + g * 8;
    const ushort_t* Brd = Bs + (size_t)(wc * NR * 16 + c) * 32 + g * 8;
    const int arow = t >> 2, acol = (t & 3) * 8;   // staging coords

    for (int k0 = 0; k0 < K; k0 += 32) {
        __syncthreads();   // previous iteration's reads done
#pragma unroll
        for (int j = 0; j < BM / 64; ++j)
            gload_lds16(A + (size_t)(m0 + j * 64 + arow) * K + k0 + acol,
                        As + (size_t)j * 2048 + t * 8);
#pragma unroll
        for (int j = 0; j < BN / 64; ++j)
            gload_lds16(Bt + (size_t)(n0 + j * 64 + arow) * K + k0 + acol,
                        Bs + (size_t)j * 2048 + t * 8);
        __syncthreads();   // staging complete (compiler drains vmcnt)

        short8 af[MR], bf[NR];
#pragma unroll
        for (int mi = 0; mi < MR; ++mi) af[mi] = *(const short8*)(Ard + mi * 512);
#pragma unroll
        for (int ni = 0; ni < NR; ++ni) bf[ni] = *(const short8*)(Brd + ni * 512);
#pragma unroll
        for (int mi = 0; mi < MR; ++mi)
#pragma unroll
            for (int ni = 0; ni < NR; ++ni)
                acc[mi][ni] = __builtin_amdgcn_mfma_f32_16x16x32_bf16(
                    af[mi], bf[ni], acc[mi][ni], 0, 0, 0);
    }

#pragma unroll
    for (int mi = 0; mi < MR; ++mi)
#pragma unroll
        for (int ni = 0; ni < NR; ++ni)
#pragma unroll
            for (int i = 0; i < 4; ++i) {
                int row = m0 + wr * MR * 16 + mi * 16 + g * 4 + i;
                int col = n0 + wc * NR * 16 + ni * 16 + c;
                float v = acc[mi][ni][i];
                if (MODE == 0) {
                    v += bias[col] + resid[(size_t)row * N + col];
                    ((float*)out0)[(size_t)row * N + col] = v;
                } else if (MODE == 1) {
                    v += bias[col];
                    v = v > 0.f ? v : 0.f;
                    ((ushort_t*)out0)[(size_t)row * N + col] = f2bf(v);
                } else {
                    int bb = row >> 11, tt = row & (TSEQ - 1);
                    ushort_t val = f2bf(v);
                    if (col < 1024) {
                        int head = col >> 6, d = col & 63;
                        ((ushort_t*)out0)[((size_t)(bb * NH + head) * TSEQ + tt) * DH + d] = val;
                    } else if (col < 2048) {
                        int head = (col - 1024) >> 6, d = col & 63;
                        ((ushort_t*)out1)[((size_t)(bb * NH + head) * TSEQ + tt) * DH + d] = val;
                    } else {
                        int head = (col - 2048) >> 6, d = col & 63;
                        ((ushort_t*)out2)[((size_t)(bb * NH + head) * DH + d) * TSEQ + tt] = val;
                    }
                }
            }
}

// ---------------------------------------------------------------------------
// Flash attention: per-wave 16 q-rows, s-tiles of 32, online softmax.
// grid (T/64=32, B*H=32), block 256.
// ---------------------------------------------------------------------------
__global__ __launch_bounds__(256) void flash_attn(
    const ushort_t* __restrict__ Q, const ushort_t* __restrict__ Kb,
    const ushort_t* __restrict__ Vt, ushort_t* __restrict__ attout)
{
    __shared__ ushort_t Plds[4][16][32];
    int w = threadIdx.x >> 6, lane = threadIdx.x & 63;
    int g = lane >> 4, c = lane & 15;
    int bh = blockIdx.y;
    int bb = bh >> 4, hh = bh & 15;
    int q0 = blockIdx.x * 64 + w * 16;
    const ushort_t* qp = Q + (size_t)bh * TSEQ * DH;
    const ushort_t* kp = Kb + (size_t)bh * TSEQ * DH;
    const ushort_t* vp = Vt + (size_t)bh * DH * TSEQ;

    short8 aq0 = *(const short8*)(qp + (size_t)(q0 + c) * DH + g * 8);
    short8 aq1 = *(const short8*)(qp + (size_t)(q0 + c) * DH + 32 + g * 8);

    float m_[4], l_[4];
    f32x4 o[4];
#pragma unroll
    for (int i = 0; i < 4; ++i) { m_[i] = -INFINITY; l_[i] = 0.f; }
#pragma unroll
    for (int nf = 0; nf < 4; ++nf) o[nf] = f32x4{0.f, 0.f, 0.f, 0.f};

    int nst = (q0 + 15) / 32 + 1;
    for (int st = 0; st < nst; ++st) {
        int s0 = st * 32;
        f32x4 sa[2];
#pragma unroll
        for (int sub = 0; sub < 2; ++sub) {
            short8 b0 = *(const short8*)(kp + (size_t)(s0 + sub * 16 + c) * DH + g * 8);
            short8 b1 = *(const short8*)(kp + (size_t)(s0 + sub * 16 + c) * DH + 32 + g * 8);
            f32x4 tacc = f32x4{0.f, 0.f, 0.f, 0.f};
            tacc = __builtin_amdgcn_mfma_f32_16x16x32_bf16(aq0, b0, tacc, 0, 0, 0);
            tacc = __builtin_amdgcn_mfma_f32_16x16x32_bf16(aq1, b1, tacc, 0, 0, 0);
            sa[sub] = tacc;
        }
        float p0s[4], p1s[4];
#pragma unroll
        for (int i = 0; i < 4; ++i) {
            int tg = q0 + g * 4 + i;
            float v0 = sa[0][i] * ATT_SCALE;
            float v1 = sa[1][i] * ATT_SCALE;
            if (s0 + c > tg) v0 = -INFINITY;
            if (s0 + 16 + c > tg) v1 = -INFINITY;
            float tmax = fmaxf(v0, v1);
#pragma unroll
            for (int d = 1; d < 16; d <<= 1) tmax = fmaxf(tmax, __shfl_xor(tmax, d));
            float mn = fmaxf(m_[i], tmax);
            float fac = expf(m_[i] - mn);
            float p0 = expf(v0 - mn), p1 = expf(v1 - mn);
            float rs = p0 + p1;
#pragma unroll
            for (int d = 1; d < 16; d <<= 1) rs += __shfl_xor(rs, d);
            l_[i] = l_[i] * fac + rs;
            m_[i] = mn;
            p0s[i] = p0; p1s[i] = p1;
#pragma unroll
            for (int nf = 0; nf < 4; ++nf) o[nf][i] *= fac;
        }
#pragma unroll
        for (int i = 0; i < 4; ++i) {
            Plds[w][g * 4 + i][c] = f2bf(p0s[i]);
            Plds[w][g * 4 + i][16 + c] = f2bf(p1s[i]);
        }
        asm volatile("s_waitcnt lgkmcnt(0)" ::: "memory");
        short8 pa = *(const short8*)(&Plds[w][c][g * 8]);
#pragma unroll
        for (int nf = 0; nf < 4; ++nf) {
            short8 vb = *(const short8*)(vp + (size_t)(nf * 16 + c) * TSEQ + s0 + g * 8);
            o[nf] = __builtin_amdgcn_mfma_f32_16x16x32_bf16(pa, vb, o[nf], 0, 0, 0);
        }
    }
#pragma unroll
    for (int nf = 0; nf < 4; ++nf)
#pragma unroll
        for (int i = 0; i < 4; ++i) {
            int tt = q0 + g * 4 + i;
            float v = o[nf][i] / l_[i];
            attout[((size_t)(bb * TSEQ + tt)) * CC + hh * DH + nf * 16 + c] = f2bf(v);
        }
}

// ---------------------------------------------------------------------------
extern "C" void kernel_launch(void* const* d_in, const int* in_sizes, int n_in,
                              void* d_out, int out_size, void* d_ws, size_t ws_size,
                              hipStream_t stream)
{
    (void)in_sizes; (void)n_in; (void)out_size; (void)ws_size;
    const float* x     = (const float*)d_in[0];
    const float* ln1_g = (const float*)d_in[1];
    const float* ln1_b = (const float*)d_in[2];
    const float* Wq    = (const float*)d_in[3];
    const float* Wk    = (const float*)d_in[4];
    const float* Wv    = (const float*)d_in[5];
    const float* Wo    = (const float*)d_in[6];
    const float* bo    = (const float*)d_in[7];
    const float* ln2_g = (const float*)d_in[8];
    const float* ln2_b = (const float*)d_in[9];
    const float* W1    = (const float*)d_in[10];
    const float* b1    = (const float*)d_in[11];
    const float* W2    = (const float*)d_in[12];
    const float* b2    = (const float*)d_in[13];

    char* p = (char*)d_ws;
    ushort_t* hbuf  = (ushort_t*)p;  p += (size_t)BT * CC * 2;          // 8 MB
    ushort_t* WqkvT = (ushort_t*)p;  p += (size_t)3 * CC * CC * 2;      // 6 MB ([3072][1024])
    ushort_t* WoT   = (ushort_t*)p;  p += (size_t)CC * CC * 2;          // 2 MB
    ushort_t* W1T   = (ushort_t*)p;  p += (size_t)CC * HID * 2;         // 8 MB
    ushort_t* W2T   = (ushort_t*)p;  p += (size_t)HID * CC * 2;         // 8 MB
    ushort_t* Qb    = (ushort_t*)p;  p += (size_t)BT * CC * 2;          // 8 MB
    ushort_t* Kbuf  = (ushort_t*)p;  p += (size_t)BT * CC * 2;          // 8 MB
    ushort_t* Vt    = (ushort_t*)p;  p += (size_t)BT * CC * 2;          // 8 MB
    ushort_t* atto  = (ushort_t*)p;  p += (size_t)BT * CC * 2;          // 8 MB
    float*    x1    = (float*)p;     p += (size_t)BT * CC * 4;          // 16 MB
    ushort_t* h2    = (ushort_t*)p;  p += (size_t)BT * CC * 2;          // 8 MB
    ushort_t* mid   = (ushort_t*)p;  p += (size_t)BT * HID * 2;         // 32 MB

    ushort_t* WqT = WqkvT;
    ushort_t* WkT = WqkvT + (size_t)CC * CC;
    ushort_t* WvT = WqkvT + (size_t)2 * CC * CC;

    dim3 blk(256);
    transpose_cvt<<<dim3(DH / 32, CC / 32, NH), blk, 0, stream>>>(Wq, WqT, CC, DH);
    transpose_cvt<<<dim3(DH / 32, CC / 32, NH), blk, 0, stream>>>(Wk, WkT, CC, DH);
    transpose_cvt<<<dim3(DH / 32, CC / 32, NH), blk, 0, stream>>>(Wv, WvT, CC, DH);
    transpose_cvt<<<dim3(CC / 32, CC / 32, 1), blk, 0, stream>>>(Wo, WoT, CC, CC);
    transpose_cvt<<<dim3(HID / 32, CC / 32, 1), blk, 0, stream>>>(W1, W1T, CC, HID);
    transpose_cvt<<<dim3(CC / 32, HID / 32, 1), blk, 0, stream>>>(W2, W2T, HID, CC);

    // LN1
    ln_kernel<<<dim3(BT), blk, 0, stream>>>(x, ln1_g, ln1_b, hbuf);
    // QKV: [4096]x[3072]x[1024], scatter epilogue
    gemm_tile<128, 128, 2, 2, 4, 4, 2><<<dim3(BT / 128, 3072 / 128), blk, 0, stream>>>(
        hbuf, WqkvT, 3072, CC, nullptr, nullptr, Qb, Kbuf, Vt);
    // flash attention
    flash_attn<<<dim3(TSEQ / 64, 2 * NH), blk, 0, stream>>>(Qb, Kbuf, Vt, atto);
    // out projection + residual -> x1 (f32)
    gemm_tile<128, 64, 4, 1, 2, 4, 0><<<dim3(BT / 128, CC / 64), blk, 0, stream>>>(
        atto, WoT, CC, CC, bo, x, (void*)x1, nullptr, nullptr);
    // LN2
    ln_kernel<<<dim3(BT), blk, 0, stream>>>(x1, ln2_g, ln2_b, h2);
    // FFN1: relu(h2 @ W1 + b1) -> mid (bf16)
    gemm_tile<128, 128, 2, 2, 4, 4, 1><<<dim3(BT / 128, HID / 128), blk, 0, stream>>>(
        h2, W1T, HID, CC, b1, nullptr, (void*)mid, nullptr, nullptr);
    // FFN2: x1 + mid @ W2 + b2 -> d_out (f32)
    gemm_tile<128, 64, 4, 1, 2, 4, 0><<<dim3(BT / 128, CC / 64), blk, 0, stream>>>(
        mid, W2T, CC, HID, b2, x1, d_out, nullptr, nullptr);
}

// Round 4
// 454.072 us; speedup vs baseline: 2.4863x; 1.0072x over previous
//
#include <hip/hip_runtime.h>

typedef unsigned short ushort_t;
typedef __attribute__((ext_vector_type(8))) short short8;
typedef __attribute__((ext_vector_type(4))) float f32x4;

#define BT 4096
#define TSEQ 2048
#define CC 1024
#define NH 16
#define DH 64
#define HID 4096
#define ATT_SCALE 0.03125f   /* C^-0.5 = 1/32 (reference scales by C, not DH) */

__device__ __forceinline__ ushort_t f2bf(float f) {
    unsigned u = __float_as_uint(f);
    u = u + 0x7fffu + ((u >> 16) & 1u);
    return (ushort_t)(u >> 16);
}

typedef const __attribute__((address_space(1))) unsigned int* gptr_t;
typedef __attribute__((address_space(3))) unsigned int* lptr_t;
__device__ __forceinline__ void gload_lds16(const void* g, void* l) {
    __builtin_amdgcn_global_load_lds((gptr_t)g, (lptr_t)l, 16, 0, 0);
}

// ---------------------------------------------------------------------------
// Tiled transpose + f32->bf16 convert:  in [R][Cn] f32  ->  out [Cn][R] bf16
// ---------------------------------------------------------------------------
__global__ __launch_bounds__(256) void transpose_cvt(
    const float* __restrict__ in, ushort_t* __restrict__ out, int R, int Cn)
{
    __shared__ float tile[32][33];
    size_t off = (size_t)blockIdx.z * R * Cn;
    int c0 = blockIdx.x * 32, r0 = blockIdx.y * 32;
    int tx = threadIdx.x & 31, ty = threadIdx.x >> 5;
#pragma unroll
    for (int q = 0; q < 4; ++q)
        tile[ty + 8 * q][tx] = in[off + (size_t)(r0 + ty + 8 * q) * Cn + c0 + tx];
    __syncthreads();
#pragma unroll
    for (int q = 0; q < 4; ++q)
        out[off + (size_t)(c0 + ty + 8 * q) * R + r0 + tx] = f2bf(tile[tx][ty + 8 * q]);
}

// ---------------------------------------------------------------------------
// LayerNorm row kernel: x f32 [rows][1024] -> out bf16.
// ---------------------------------------------------------------------------
__global__ __launch_bounds__(256) void ln_kernel(
    const float* __restrict__ x, const float* __restrict__ g,
    const float* __restrict__ b, ushort_t* __restrict__ out)
{
    int row = blockIdx.x;
    const float4 xv = ((const float4*)(x + (size_t)row * CC))[threadIdx.x];
    float s = xv.x + xv.y + xv.z + xv.w;
    float s2 = xv.x * xv.x + xv.y * xv.y + xv.z * xv.z + xv.w * xv.w;
#pragma unroll
    for (int d = 1; d < 64; d <<= 1) {
        s += __shfl_xor(s, d);
        s2 += __shfl_xor(s2, d);
    }
    __shared__ float ps[4], ps2[4];
    int w = threadIdx.x >> 6, lane = threadIdx.x & 63;
    if (lane == 0) { ps[w] = s; ps2[w] = s2; }
    __syncthreads();
    s = ps[0] + ps[1] + ps[2] + ps[3];
    s2 = ps2[0] + ps2[1] + ps2[2] + ps2[3];
    float mu = s * (1.0f / CC);
    float var = s2 * (1.0f / CC) - mu * mu;
    float rs = rsqrtf(var + 1e-5f);
    int c = threadIdx.x * 4;
    const float4 gv = ((const float4*)g)[threadIdx.x];
    const float4 bv = ((const float4*)b)[threadIdx.x];
    ushort_t u0 = f2bf((xv.x - mu) * rs * gv.x + bv.x);
    ushort_t u1 = f2bf((xv.y - mu) * rs * gv.y + bv.y);
    ushort_t u2 = f2bf((xv.z - mu) * rs * gv.z + bv.z);
    ushort_t u3 = f2bf((xv.w - mu) * rs * gv.w + bv.w);
    unsigned lo = (unsigned)u0 | ((unsigned)u1 << 16);
    unsigned hi = (unsigned)u2 | ((unsigned)u3 << 16);
    ((uint2*)(out + (size_t)row * CC + c))[0] = make_uint2(lo, hi);
}

// ---------------------------------------------------------------------------
// LDS-staged NT GEMM (m97 structure): BMxBN tile, BK=32, 256 threads.
// MODE 0: f32 out = acc + bias[n] + resid[m][n]
// MODE 1: bf16 out = relu(acc + bias[n])
// MODE 2: QKV scatter (Q prescaled by ATT_SCALE)
// ---------------------------------------------------------------------------
template <int BM, int BN, int WM, int WN, int MR, int NR, int MODE>
__global__ __launch_bounds__(256) void gemm_tile(
    const ushort_t* __restrict__ A, const ushort_t* __restrict__ Bt,
    int N, int K,
    const float* __restrict__ bias, const float* __restrict__ resid,
    void* __restrict__ out0, void* __restrict__ out1, void* __restrict__ out2)
{
    static_assert(WM * WN == 4 && WM * MR * 16 == BM && WN * NR * 16 == BN, "geom");
    __shared__ ushort_t As[BM * 32];
    __shared__ ushort_t Bs[BN * 32];

    const int t = threadIdx.x;
    const int w = t >> 6, lane = t & 63, g = lane >> 4, c = lane & 15;
    const int wr = w / WN, wc = w % WN;
    const int m0 = blockIdx.x * BM;
    const int n0 = blockIdx.y * BN;

    f32x4 acc[MR][NR];
#pragma unroll
    for (int mi = 0; mi < MR; ++mi)
#pragma unroll
        for (int ni = 0; ni < NR; ++ni) acc[mi][ni] = f32x4{0.f, 0.f, 0.f, 0.f};

    const ushort_t* Ard = As + (size_t)(wr * MR * 16 + c) * 32 + g * 8;
    const ushort_t* Brd = Bs + (size_t)(wc * NR * 16 + c) * 32 + g * 8;
    const int arow = t >> 2, acol = (t & 3) * 8;

    for (int k0 = 0; k0 < K; k0 += 32) {
        __syncthreads();
#pragma unroll
        for (int j = 0; j < BM / 64; ++j)
            gload_lds16(A + (size_t)(m0 + j * 64 + arow) * K + k0 + acol,
                        As + (size_t)j * 2048 + t * 8);
#pragma unroll
        for (int j = 0; j < BN / 64; ++j)
            gload_lds16(Bt + (size_t)(n0 + j * 64 + arow) * K + k0 + acol,
                        Bs + (size_t)j * 2048 + t * 8);
        __syncthreads();

        short8 af[MR], bf[NR];
#pragma unroll
        for (int mi = 0; mi < MR; ++mi) af[mi] = *(const short8*)(Ard + mi * 512);
#pragma unroll
        for (int ni = 0; ni < NR; ++ni) bf[ni] = *(const short8*)(Brd + ni * 512);
#pragma unroll
        for (int mi = 0; mi < MR; ++mi)
#pragma unroll
            for (int ni = 0; ni < NR; ++ni)
                acc[mi][ni] = __builtin_amdgcn_mfma_f32_16x16x32_bf16(
                    af[mi], bf[ni], acc[mi][ni], 0, 0, 0);
    }

#pragma unroll
    for (int mi = 0; mi < MR; ++mi)
#pragma unroll
        for (int ni = 0; ni < NR; ++ni)
#pragma unroll
            for (int i = 0; i < 4; ++i) {
                int row = m0 + wr * MR * 16 + mi * 16 + g * 4 + i;
                int col = n0 + wc * NR * 16 + ni * 16 + c;
                float v = acc[mi][ni][i];
                if (MODE == 0) {
                    v += bias[col] + resid[(size_t)row * N + col];
                    ((float*)out0)[(size_t)row * N + col] = v;
                } else if (MODE == 1) {
                    v += bias[col];
                    v = v > 0.f ? v : 0.f;
                    ((ushort_t*)out0)[(size_t)row * N + col] = f2bf(v);
                } else {
                    int bb = row >> 11, tt = row & (TSEQ - 1);
                    if (col < 1024) {
                        int head = col >> 6, d = col & 63;
                        ((ushort_t*)out0)[((size_t)(bb * NH + head) * TSEQ + tt) * DH + d] =
                            f2bf(v * ATT_SCALE);
                    } else if (col < 2048) {
                        int head = (col - 1024) >> 6, d = col & 63;
                        ((ushort_t*)out1)[((size_t)(bb * NH + head) * TSEQ + tt) * DH + d] = f2bf(v);
                    } else {
                        int head = (col - 2048) >> 6, d = col & 63;
                        ((ushort_t*)out2)[((size_t)(bb * NH + head) * DH + d) * TSEQ + tt] = f2bf(v);
                    }
                }
            }
}

// ---------------------------------------------------------------------------
// Flash attention, swapped QK^T: mfma(K,Q) -> S^T so each lane owns one q-row
// (q = q0 + (lane&15)); softmax reductions are 8 in-register + 2 shfl steps.
// Per-wave 16 q-rows, s-tiles of 32, defer-max (THR=8), LDS P-transpose.
// grid (T/64, B*H), block 256.
// ---------------------------------------------------------------------------
__global__ __launch_bounds__(256, 4) void flash_attn(
    const ushort_t* __restrict__ Q, const ushort_t* __restrict__ Kb,
    const ushort_t* __restrict__ Vt, ushort_t* __restrict__ attout)
{
    __shared__ ushort_t Plds[4][16 * 48];   // row stride 48 elems (96 B)
    const int w = threadIdx.x >> 6, lane = threadIdx.x & 63;
    const int g = lane >> 4, c = lane & 15;
    const int bh = blockIdx.y, bb = bh >> 4, hh = bh & 15;
    const int q0 = blockIdx.x * 64 + w * 16;
    const ushort_t* qp = Q + (size_t)bh * TSEQ * DH;
    const ushort_t* kp = Kb + (size_t)bh * TSEQ * DH;
    const ushort_t* vp = Vt + (size_t)bh * DH * TSEQ;

    // Q as MFMA B-operand: col = q (lane&15), k = d
    const short8 bq0 = *(const short8*)(qp + (size_t)(q0 + c) * DH + g * 8);
    const short8 bq1 = *(const short8*)(qp + (size_t)(q0 + c) * DH + 32 + g * 8);

    float m_ = -INFINITY, l_ = 0.f;
    f32x4 o[4];
#pragma unroll
    for (int nf = 0; nf < 4; ++nf) o[nf] = f32x4{0.f, 0.f, 0.f, 0.f};

    ushort_t* pw = &Plds[w][c * 48];

    const int nst = (q0 >> 5) + 1;
    for (int st = 0; st < nst; ++st) {
        const int s0 = st * 32;
        // K as A-operand: row = s (lane&15), k = d  ->  D[s_local][q_local]
        short8 k00 = *(const short8*)(kp + (size_t)(s0 + c) * DH + g * 8);
        short8 k01 = *(const short8*)(kp + (size_t)(s0 + c) * DH + 32 + g * 8);
        short8 k10 = *(const short8*)(kp + (size_t)(s0 + 16 + c) * DH + g * 8);
        short8 k11 = *(const short8*)(kp + (size_t)(s0 + 16 + c) * DH + 32 + g * 8);
        f32x4 sa0 = f32x4{0.f, 0.f, 0.f, 0.f};
        f32x4 sa1 = f32x4{0.f, 0.f, 0.f, 0.f};
        sa0 = __builtin_amdgcn_mfma_f32_16x16x32_bf16(k00, bq0, sa0, 0, 0, 0);
        sa0 = __builtin_amdgcn_mfma_f32_16x16x32_bf16(k01, bq1, sa0, 0, 0, 0);
        sa1 = __builtin_amdgcn_mfma_f32_16x16x32_bf16(k10, bq0, sa1, 0, 0, 0);
        sa1 = __builtin_amdgcn_mfma_f32_16x16x32_bf16(k11, bq1, sa1, 0, 0, 0);

        // per-lane: 8 scores of q-row (q0+c), s = s0 + sub*16 + 4g + i
        float pv8[8];
#pragma unroll
        for (int i = 0; i < 4; ++i) { pv8[i] = sa0[i]; pv8[4 + i] = sa1[i]; }
        if (s0 + 31 > q0) {   // tile touches diagonal -> causal mask
#pragma unroll
            for (int sub = 0; sub < 2; ++sub)
#pragma unroll
                for (int i = 0; i < 4; ++i)
                    if (s0 + sub * 16 + 4 * g + i > q0 + c) pv8[sub * 4 + i] = -INFINITY;
        }
        float tmax = fmaxf(fmaxf(fmaxf(pv8[0], pv8[1]), fmaxf(pv8[2], pv8[3])),
                           fmaxf(fmaxf(pv8[4], pv8[5]), fmaxf(pv8[6], pv8[7])));
        tmax = fmaxf(tmax, __shfl_xor(tmax, 16));
        tmax = fmaxf(tmax, __shfl_xor(tmax, 32));
        if (!__all(tmax - m_ <= 8.0f)) {   // defer-max: rescale only on max jump
            float mn = fmaxf(m_, tmax);
            float fac = __expf(m_ - mn);
            m_ = mn;
            l_ *= fac;
#pragma unroll
            for (int i = 0; i < 4; ++i) {
                float fr = __shfl(fac, 4 * g + i);   // fac for output row q0+4g+i
#pragma unroll
                for (int nf = 0; nf < 4; ++nf) o[nf][i] *= fr;
            }
        }
        float p8[8], rs = 0.f;
#pragma unroll
        for (int j = 0; j < 8; ++j) { p8[j] = __expf(pv8[j] - m_); rs += p8[j]; }
        rs += __shfl_xor(rs, 16);
        rs += __shfl_xor(rs, 32);
        l_ += rs;

        // P -> bf16 pairs (truncate), LDS transpose: row q=c, cols 4g.. / 16+4g..
        unsigned w0 = (__float_as_uint(p8[0]) >> 16) | (__float_as_uint(p8[1]) & 0xffff0000u);
        unsigned w1 = (__float_as_uint(p8[2]) >> 16) | (__float_as_uint(p8[3]) & 0xffff0000u);
        unsigned w2 = (__float_as_uint(p8[4]) >> 16) | (__float_as_uint(p8[5]) & 0xffff0000u);
        unsigned w3 = (__float_as_uint(p8[6]) >> 16) | (__float_as_uint(p8[7]) & 0xffff0000u);
        *(uint2*)(pw + 4 * g) = make_uint2(w0, w1);
        *(uint2*)(pw + 16 + 4 * g) = make_uint2(w2, w3);
        asm volatile("s_waitcnt lgkmcnt(0)" ::: "memory");
        short8 pa = *(const short8*)(&Plds[w][c * 48 + g * 8]);
#pragma unroll
        for (int nf = 0; nf < 4; ++nf) {
            short8 vb = *(const short8*)(vp + (size_t)(nf * 16 + c) * TSEQ + s0 + g * 8);
            o[nf] = __builtin_amdgcn_mfma_f32_16x16x32_bf16(pa, vb, o[nf], 0, 0, 0);
        }
    }

#pragma unroll
    for (int i = 0; i < 4; ++i) {
        float rl = 1.0f / __shfl(l_, 4 * g + i);   // l for output row q0+4g+i
        int tt = q0 + 4 * g + i;
#pragma unroll
        for (int nf = 0; nf < 4; ++nf)
            attout[((size_t)(bb * TSEQ + tt)) * CC + hh * DH + nf * 16 + c] =
                f2bf(o[nf][i] * rl);
    }
}

// ---------------------------------------------------------------------------
extern "C" void kernel_launch(void* const* d_in, const int* in_sizes, int n_in,
                              void* d_out, int out_size, void* d_ws, size_t ws_size,
                              hipStream_t stream)
{
    (void)in_sizes; (void)n_in; (void)out_size; (void)ws_size;
    const float* x     = (const float*)d_in[0];
    const float* ln1_g = (const float*)d_in[1];
    const float* ln1_b = (const float*)d_in[2];
    const float* Wq    = (const float*)d_in[3];
    const float* Wk    = (const float*)d_in[4];
    const float* Wv    = (const float*)d_in[5];
    const float* Wo    = (const float*)d_in[6];
    const float* bo    = (const float*)d_in[7];
    const float* ln2_g = (const float*)d_in[8];
    const float* ln2_b = (const float*)d_in[9];
    const float* W1    = (const float*)d_in[10];
    const float* b1    = (const float*)d_in[11];
    const float* W2    = (const float*)d_in[12];
    const float* b2    = (const float*)d_in[13];

    char* p = (char*)d_ws;
    ushort_t* hbuf  = (ushort_t*)p;  p += (size_t)BT * CC * 2;
    ushort_t* WqkvT = (ushort_t*)p;  p += (size_t)3 * CC * CC * 2;
    ushort_t* WoT   = (ushort_t*)p;  p += (size_t)CC * CC * 2;
    ushort_t* W1T   = (ushort_t*)p;  p += (size_t)CC * HID * 2;
    ushort_t* W2T   = (ushort_t*)p;  p += (size_t)HID * CC * 2;
    ushort_t* Qb    = (ushort_t*)p;  p += (size_t)BT * CC * 2;
    ushort_t* Kbuf  = (ushort_t*)p;  p += (size_t)BT * CC * 2;
    ushort_t* Vt    = (ushort_t*)p;  p += (size_t)BT * CC * 2;
    ushort_t* atto  = (ushort_t*)p;  p += (size_t)BT * CC * 2;
    float*    x1    = (float*)p;     p += (size_t)BT * CC * 4;
    ushort_t* h2    = (ushort_t*)p;  p += (size_t)BT * CC * 2;
    ushort_t* mid   = (ushort_t*)p;  p += (size_t)BT * HID * 2;

    ushort_t* WqT = WqkvT;
    ushort_t* WkT = WqkvT + (size_t)CC * CC;
    ushort_t* WvT = WqkvT + (size_t)2 * CC * CC;

    dim3 blk(256);
    transpose_cvt<<<dim3(DH / 32, CC / 32, NH), blk, 0, stream>>>(Wq, WqT, CC, DH);
    transpose_cvt<<<dim3(DH / 32, CC / 32, NH), blk, 0, stream>>>(Wk, WkT, CC, DH);
    transpose_cvt<<<dim3(DH / 32, CC / 32, NH), blk, 0, stream>>>(Wv, WvT, CC, DH);
    transpose_cvt<<<dim3(CC / 32, CC / 32, 1), blk, 0, stream>>>(Wo, WoT, CC, CC);
    transpose_cvt<<<dim3(HID / 32, CC / 32, 1), blk, 0, stream>>>(W1, W1T, CC, HID);
    transpose_cvt<<<dim3(CC / 32, HID / 32, 1), blk, 0, stream>>>(W2, W2T, HID, CC);

    ln_kernel<<<dim3(BT), blk, 0, stream>>>(x, ln1_g, ln1_b, hbuf);
    gemm_tile<128, 128, 2, 2, 4, 4, 2><<<dim3(BT / 128, 3072 / 128), blk, 0, stream>>>(
        hbuf, WqkvT, 3072, CC, nullptr, nullptr, Qb, Kbuf, Vt);
    flash_attn<<<dim3(TSEQ / 64, 2 * NH), blk, 0, stream>>>(Qb, Kbuf, Vt, atto);
    gemm_tile<128, 64, 4, 1, 2, 4, 0><<<dim3(BT / 128, CC / 64), blk, 0, stream>>>(
        atto, WoT, CC, CC, bo, x, (void*)x1, nullptr, nullptr);
    ln_kernel<<<dim3(BT), blk, 0, stream>>>(x1, ln2_g, ln2_b, h2);
    gemm_tile<128, 128, 2, 2, 4, 4, 1><<<dim3(BT / 128, HID / 128), blk, 0, stream>>>(
        h2, W1T, HID, CC, b1, nullptr, (void*)mid, nullptr, nullptr);
    gemm_tile<128, 64, 4, 1, 2, 4, 0><<<dim3(BT / 128, CC / 64), blk, 0, stream>>>(
        mid, W2T, CC, HID, b2, x1, d_out, nullptr, nullptr);
}

// Round 5
// 373.075 us; speedup vs baseline: 3.0261x; 1.2171x over previous
//
#include <hip/hip_runtime.h>

typedef unsigned short ushort_t;
typedef __attribute__((ext_vector_type(8))) short short8;
typedef __attribute__((ext_vector_type(4))) float f32x4;

#define BT 4096
#define TSEQ 2048
#define CC 1024
#define NH 16
#define DH 64
#define HID 4096
#define ATT_SCALE 0.03125f   /* C^-0.5 = 1/32 (reference scales by C, not DH) */

__device__ __forceinline__ ushort_t f2bf(float f) {
    unsigned u = __float_as_uint(f);
    u = u + 0x7fffu + ((u >> 16) & 1u);
    return (ushort_t)(u >> 16);
}

typedef const __attribute__((address_space(1))) unsigned int* gptr_t;
typedef __attribute__((address_space(3))) unsigned int* lptr_t;
__device__ __forceinline__ void gload_lds16(const void* g, void* l) {
    __builtin_amdgcn_global_load_lds((gptr_t)g, (lptr_t)l, 16, 0, 0);
}

// ---------------------------------------------------------------------------
// Tiled transpose + f32->bf16 convert:  in [R][Cn] f32  ->  out [Cn][R] bf16
// ---------------------------------------------------------------------------
__global__ __launch_bounds__(256) void transpose_cvt(
    const float* __restrict__ in, ushort_t* __restrict__ out, int R, int Cn)
{
    __shared__ float tile[32][33];
    size_t off = (size_t)blockIdx.z * R * Cn;
    int c0 = blockIdx.x * 32, r0 = blockIdx.y * 32;
    int tx = threadIdx.x & 31, ty = threadIdx.x >> 5;
#pragma unroll
    for (int q = 0; q < 4; ++q)
        tile[ty + 8 * q][tx] = in[off + (size_t)(r0 + ty + 8 * q) * Cn + c0 + tx];
    __syncthreads();
#pragma unroll
    for (int q = 0; q < 4; ++q)
        out[off + (size_t)(c0 + ty + 8 * q) * R + r0 + tx] = f2bf(tile[tx][ty + 8 * q]);
}

// ---------------------------------------------------------------------------
// LayerNorm row kernel: x f32 [rows][1024] -> out bf16.
// ---------------------------------------------------------------------------
__global__ __launch_bounds__(256) void ln_kernel(
    const float* __restrict__ x, const float* __restrict__ g,
    const float* __restrict__ b, ushort_t* __restrict__ out)
{
    int row = blockIdx.x;
    const float4 xv = ((const float4*)(x + (size_t)row * CC))[threadIdx.x];
    float s = xv.x + xv.y + xv.z + xv.w;
    float s2 = xv.x * xv.x + xv.y * xv.y + xv.z * xv.z + xv.w * xv.w;
#pragma unroll
    for (int d = 1; d < 64; d <<= 1) {
        s += __shfl_xor(s, d);
        s2 += __shfl_xor(s2, d);
    }
    __shared__ float ps[4], ps2[4];
    int w = threadIdx.x >> 6, lane = threadIdx.x & 63;
    if (lane == 0) { ps[w] = s; ps2[w] = s2; }
    __syncthreads();
    s = ps[0] + ps[1] + ps[2] + ps[3];
    s2 = ps2[0] + ps2[1] + ps2[2] + ps2[3];
    float mu = s * (1.0f / CC);
    float var = s2 * (1.0f / CC) - mu * mu;
    float rs = rsqrtf(var + 1e-5f);
    int c = threadIdx.x * 4;
    const float4 gv = ((const float4*)g)[threadIdx.x];
    const float4 bv = ((const float4*)b)[threadIdx.x];
    ushort_t u0 = f2bf((xv.x - mu) * rs * gv.x + bv.x);
    ushort_t u1 = f2bf((xv.y - mu) * rs * gv.y + bv.y);
    ushort_t u2 = f2bf((xv.z - mu) * rs * gv.z + bv.z);
    ushort_t u3 = f2bf((xv.w - mu) * rs * gv.w + bv.w);
    unsigned lo = (unsigned)u0 | ((unsigned)u1 << 16);
    unsigned hi = (unsigned)u2 | ((unsigned)u3 << 16);
    ((uint2*)(out + (size_t)row * CC + c))[0] = make_uint2(lo, hi);
}

// ---------------------------------------------------------------------------
// LDS-staged NT GEMM (m97 structure): BMxBN tile, BK=32, 256 threads.
// MODE 0: f32 out = acc + bias[n] + resid[m][n]
// MODE 1: bf16 out = relu(acc + bias[n])
// MODE 2: QKV scatter (Q prescaled by ATT_SCALE)
// ---------------------------------------------------------------------------
template <int BM, int BN, int WM, int WN, int MR, int NR, int MODE>
__global__ __launch_bounds__(256) void gemm_tile(
    const ushort_t* __restrict__ A, const ushort_t* __restrict__ Bt,
    int N, int K,
    const float* __restrict__ bias, const float* __restrict__ resid,
    void* __restrict__ out0, void* __restrict__ out1, void* __restrict__ out2)
{
    static_assert(WM * WN == 4 && WM * MR * 16 == BM && WN * NR * 16 == BN, "geom");
    __shared__ ushort_t As[BM * 32];
    __shared__ ushort_t Bs[BN * 32];

    const int t = threadIdx.x;
    const int w = t >> 6, lane = t & 63, g = lane >> 4, c = lane & 15;
    const int wr = w / WN, wc = w % WN;
    const int m0 = blockIdx.x * BM;
    const int n0 = blockIdx.y * BN;

    f32x4 acc[MR][NR];
#pragma unroll
    for (int mi = 0; mi < MR; ++mi)
#pragma unroll
        for (int ni = 0; ni < NR; ++ni) acc[mi][ni] = f32x4{0.f, 0.f, 0.f, 0.f};

    const ushort_t* Ard = As + (size_t)(wr * MR * 16 + c) * 32 + g * 8;
    const ushort_t* Brd = Bs + (size_t)(wc * NR * 16 + c) * 32 + g * 8;
    const int arow = t >> 2, acol = (t & 3) * 8;

    for (int k0 = 0; k0 < K; k0 += 32) {
        __syncthreads();
#pragma unroll
        for (int j = 0; j < BM / 64; ++j)
            gload_lds16(A + (size_t)(m0 + j * 64 + arow) * K + k0 + acol,
                        As + (size_t)j * 2048 + t * 8);
#pragma unroll
        for (int j = 0; j < BN / 64; ++j)
            gload_lds16(Bt + (size_t)(n0 + j * 64 + arow) * K + k0 + acol,
                        Bs + (size_t)j * 2048 + t * 8);
        __syncthreads();

        short8 af[MR], bf[NR];
#pragma unroll
        for (int mi = 0; mi < MR; ++mi) af[mi] = *(const short8*)(Ard + mi * 512);
#pragma unroll
        for (int ni = 0; ni < NR; ++ni) bf[ni] = *(const short8*)(Brd + ni * 512);
#pragma unroll
        for (int mi = 0; mi < MR; ++mi)
#pragma unroll
            for (int ni = 0; ni < NR; ++ni)
                acc[mi][ni] = __builtin_amdgcn_mfma_f32_16x16x32_bf16(
                    af[mi], bf[ni], acc[mi][ni], 0, 0, 0);
    }

#pragma unroll
    for (int mi = 0; mi < MR; ++mi)
#pragma unroll
        for (int ni = 0; ni < NR; ++ni)
#pragma unroll
            for (int i = 0; i < 4; ++i) {
                int row = m0 + wr * MR * 16 + mi * 16 + g * 4 + i;
                int col = n0 + wc * NR * 16 + ni * 16 + c;
                float v = acc[mi][ni][i];
                if (MODE == 0) {
                    v += bias[col] + resid[(size_t)row * N + col];
                    ((float*)out0)[(size_t)row * N + col] = v;
                } else if (MODE == 1) {
                    v += bias[col];
                    v = v > 0.f ? v : 0.f;
                    ((ushort_t*)out0)[(size_t)row * N + col] = f2bf(v);
                } else {
                    int bb = row >> 11, tt = row & (TSEQ - 1);
                    if (col < 1024) {
                        int head = col >> 6, d = col & 63;
                        ((ushort_t*)out0)[((size_t)(bb * NH + head) * TSEQ + tt) * DH + d] =
                            f2bf(v * ATT_SCALE);
                    } else if (col < 2048) {
                        int head = (col - 1024) >> 6, d = col & 63;
                        ((ushort_t*)out1)[((size_t)(bb * NH + head) * TSEQ + tt) * DH + d] = f2bf(v);
                    } else {
                        int head = (col - 2048) >> 6, d = col & 63;
                        ((ushort_t*)out2)[((size_t)(bb * NH + head) * DH + d) * TSEQ + tt] = f2bf(v);
                    }
                }
            }
}

// ---------------------------------------------------------------------------
// Flash attention v3: swapped QK^T (lane owns one q-row), s-tile 64,
// K register double-buffer (cross-iter prefetch), V same-iter prefetch,
// defer-max, LDS P-transpose (stride 72).  grid (B*H, T/64) -- bh-major for
// CU load balance.  block 256 = 4 waves x 16 q-rows.
// ---------------------------------------------------------------------------
__global__ __launch_bounds__(256) void flash_attn(
    const ushort_t* __restrict__ Q, const ushort_t* __restrict__ Kb,
    const ushort_t* __restrict__ Vt, ushort_t* __restrict__ attout)
{
    __shared__ ushort_t Plds[4][16 * 72];
    const int w = threadIdx.x >> 6, lane = threadIdx.x & 63;
    const int g = lane >> 4, c = lane & 15;
    const int bh = blockIdx.x, bb = bh >> 4, hh = bh & 15;
    const int q0 = blockIdx.y * 64 + w * 16;
    const ushort_t* qp = Q + (size_t)bh * TSEQ * DH;
    const ushort_t* kp = Kb + (size_t)bh * TSEQ * DH;
    const ushort_t* vp = Vt + (size_t)bh * DH * TSEQ;

    // Q as MFMA B-operand: col = q (lane&15), k = d
    const short8 bq0 = *(const short8*)(qp + (size_t)(q0 + c) * DH + g * 8);
    const short8 bq1 = *(const short8*)(qp + (size_t)(q0 + c) * DH + 32 + g * 8);

    float m_ = -INFINITY, l_ = 0.f;
    f32x4 o[4];
#pragma unroll
    for (int nf = 0; nf < 4; ++nf) o[nf] = f32x4{0.f, 0.f, 0.f, 0.f};

    const int nst = q0 / 64 + 1;
    ushort_t* pw = &Plds[w][c * 72];

    short8 kkA[4][2], kkB[4][2];
#pragma unroll
    for (int sub = 0; sub < 4; ++sub)
#pragma unroll
        for (int ks = 0; ks < 2; ++ks)
            kkA[sub][ks] = *(const short8*)(kp + (size_t)(16 * sub + c) * DH + ks * 32 + g * 8);

    auto body = [&](int st, short8 (&kc)[4][2], short8 (&kn)[4][2]) {
        const int S0 = st * 64;
        // V for current tile: issued first so its vmcnt wait never drains K-prefetch
        short8 vv[4][2];
#pragma unroll
        for (int nf = 0; nf < 4; ++nf)
#pragma unroll
            for (int ks = 0; ks < 2; ++ks)
                vv[nf][ks] = *(const short8*)(vp + (size_t)(nf * 16 + c) * TSEQ + S0 + ks * 32 + g * 8);
        // K prefetch for next tile
        if (st + 1 < nst) {
#pragma unroll
            for (int sub = 0; sub < 4; ++sub)
#pragma unroll
                for (int ks = 0; ks < 2; ++ks)
                    kn[sub][ks] = *(const short8*)(kp + (size_t)(S0 + 64 + 16 * sub + c) * DH + ks * 32 + g * 8);
        }
        // QK^T (swapped): D[s_local][q_local], lane holds rows 16sub+4g+i, col q=c
        f32x4 sa[4];
#pragma unroll
        for (int sub = 0; sub < 4; ++sub) {
            f32x4 t0 = f32x4{0.f, 0.f, 0.f, 0.f};
            t0 = __builtin_amdgcn_mfma_f32_16x16x32_bf16(kc[sub][0], bq0, t0, 0, 0, 0);
            t0 = __builtin_amdgcn_mfma_f32_16x16x32_bf16(kc[sub][1], bq1, t0, 0, 0, 0);
            sa[sub] = t0;
        }
        float pvv[16];
#pragma unroll
        for (int sub = 0; sub < 4; ++sub)
#pragma unroll
            for (int i = 0; i < 4; ++i) pvv[4 * sub + i] = sa[sub][i];
        if (st == nst - 1) {   // only the diagonal tile needs masking
#pragma unroll
            for (int sub = 0; sub < 4; ++sub)
#pragma unroll
                for (int i = 0; i < 4; ++i)
                    if (S0 + 16 * sub + 4 * g + i > q0 + c) pvv[4 * sub + i] = -INFINITY;
        }
        float tmax = pvv[0];
#pragma unroll
        for (int j = 1; j < 16; ++j) tmax = fmaxf(tmax, pvv[j]);
        tmax = fmaxf(tmax, __shfl_xor(tmax, 16));
        tmax = fmaxf(tmax, __shfl_xor(tmax, 32));
        if (!__all(tmax - m_ <= 8.0f)) {   // defer-max
            float mn = fmaxf(m_, tmax);
            float fac = __expf(m_ - mn);
            m_ = mn;
            l_ *= fac;
#pragma unroll
            for (int i = 0; i < 4; ++i) {
                float fr = __shfl(fac, 4 * g + i);
#pragma unroll
                for (int nf = 0; nf < 4; ++nf) o[nf][i] *= fr;
            }
        }
        float pp[16], rs = 0.f;
#pragma unroll
        for (int j = 0; j < 16; ++j) { pp[j] = __expf(pvv[j] - m_); rs += pp[j]; }
        rs += __shfl_xor(rs, 16);
        rs += __shfl_xor(rs, 32);
        l_ += rs;
        // P -> bf16 (truncate), LDS transpose: row q=c gets s_local 16sub+4g+i
#pragma unroll
        for (int sub = 0; sub < 4; ++sub) {
            unsigned lo = (__float_as_uint(pp[4 * sub + 0]) >> 16) |
                          (__float_as_uint(pp[4 * sub + 1]) & 0xffff0000u);
            unsigned hi = (__float_as_uint(pp[4 * sub + 2]) >> 16) |
                          (__float_as_uint(pp[4 * sub + 3]) & 0xffff0000u);
            *(uint2*)(pw + 16 * sub + 4 * g) = make_uint2(lo, hi);
        }
        asm volatile("s_waitcnt lgkmcnt(0)" ::: "memory");
        short8 pa0 = *(const short8*)(&Plds[w][c * 72 + g * 8]);
        short8 pa1 = *(const short8*)(&Plds[w][c * 72 + 32 + g * 8]);
#pragma unroll
        for (int nf = 0; nf < 4; ++nf) {
            o[nf] = __builtin_amdgcn_mfma_f32_16x16x32_bf16(pa0, vv[nf][0], o[nf], 0, 0, 0);
            o[nf] = __builtin_amdgcn_mfma_f32_16x16x32_bf16(pa1, vv[nf][1], o[nf], 0, 0, 0);
        }
    };

    for (int st = 0; st < nst; st += 2) {
        body(st, kkA, kkB);
        if (st + 1 < nst) body(st + 1, kkB, kkA);
    }

#pragma unroll
    for (int i = 0; i < 4; ++i) {
        float rl = 1.0f / __shfl(l_, 4 * g + i);   // l for output row q0+4g+i
        int tt = q0 + 4 * g + i;
#pragma unroll
        for (int nf = 0; nf < 4; ++nf)
            attout[((size_t)(bb * TSEQ + tt)) * CC + hh * DH + nf * 16 + c] =
                f2bf(o[nf][i] * rl);
    }
}

// ---------------------------------------------------------------------------
extern "C" void kernel_launch(void* const* d_in, const int* in_sizes, int n_in,
                              void* d_out, int out_size, void* d_ws, size_t ws_size,
                              hipStream_t stream)
{
    (void)in_sizes; (void)n_in; (void)out_size; (void)ws_size;
    const float* x     = (const float*)d_in[0];
    const float* ln1_g = (const float*)d_in[1];
    const float* ln1_b = (const float*)d_in[2];
    const float* Wq    = (const float*)d_in[3];
    const float* Wk    = (const float*)d_in[4];
    const float* Wv    = (const float*)d_in[5];
    const float* Wo    = (const float*)d_in[6];
    const float* bo    = (const float*)d_in[7];
    const float* ln2_g = (const float*)d_in[8];
    const float* ln2_b = (const float*)d_in[9];
    const float* W1    = (const float*)d_in[10];
    const float* b1    = (const float*)d_in[11];
    const float* W2    = (const float*)d_in[12];
    const float* b2    = (const float*)d_in[13];

    char* p = (char*)d_ws;
    ushort_t* hbuf  = (ushort_t*)p;  p += (size_t)BT * CC * 2;
    ushort_t* WqkvT = (ushort_t*)p;  p += (size_t)3 * CC * CC * 2;
    ushort_t* WoT   = (ushort_t*)p;  p += (size_t)CC * CC * 2;
    ushort_t* W1T   = (ushort_t*)p;  p += (size_t)CC * HID * 2;
    ushort_t* W2T   = (ushort_t*)p;  p += (size_t)HID * CC * 2;
    ushort_t* Qb    = (ushort_t*)p;  p += (size_t)BT * CC * 2;
    ushort_t* Kbuf  = (ushort_t*)p;  p += (size_t)BT * CC * 2;
    ushort_t* Vt    = (ushort_t*)p;  p += (size_t)BT * CC * 2;
    ushort_t* atto  = (ushort_t*)p;  p += (size_t)BT * CC * 2;
    float*    x1    = (float*)p;     p += (size_t)BT * CC * 4;
    ushort_t* h2    = (ushort_t*)p;  p += (size_t)BT * CC * 2;
    ushort_t* mid   = (ushort_t*)p;  p += (size_t)BT * HID * 2;

    ushort_t* WqT = WqkvT;
    ushort_t* WkT = WqkvT + (size_t)CC * CC;
    ushort_t* WvT = WqkvT + (size_t)2 * CC * CC;

    dim3 blk(256);
    transpose_cvt<<<dim3(DH / 32, CC / 32, NH), blk, 0, stream>>>(Wq, WqT, CC, DH);
    transpose_cvt<<<dim3(DH / 32, CC / 32, NH), blk, 0, stream>>>(Wk, WkT, CC, DH);
    transpose_cvt<<<dim3(DH / 32, CC / 32, NH), blk, 0, stream>>>(Wv, WvT, CC, DH);
    transpose_cvt<<<dim3(CC / 32, CC / 32, 1), blk, 0, stream>>>(Wo, WoT, CC, CC);
    transpose_cvt<<<dim3(HID / 32, CC / 32, 1), blk, 0, stream>>>(W1, W1T, CC, HID);
    transpose_cvt<<<dim3(CC / 32, HID / 32, 1), blk, 0, stream>>>(W2, W2T, HID, CC);

    ln_kernel<<<dim3(BT), blk, 0, stream>>>(x, ln1_g, ln1_b, hbuf);
    gemm_tile<128, 128, 2, 2, 4, 4, 2><<<dim3(BT / 128, 3072 / 128), blk, 0, stream>>>(
        hbuf, WqkvT, 3072, CC, nullptr, nullptr, Qb, Kbuf, Vt);
    flash_attn<<<dim3(2 * NH, TSEQ / 64), blk, 0, stream>>>(Qb, Kbuf, Vt, atto);
    gemm_tile<128, 64, 4, 1, 2, 4, 0><<<dim3(BT / 128, CC / 64), blk, 0, stream>>>(
        atto, WoT, CC, CC, bo, x, (void*)x1, nullptr, nullptr);
    ln_kernel<<<dim3(BT), blk, 0, stream>>>(x1, ln2_g, ln2_b, h2);
    gemm_tile<128, 128, 2, 2, 4, 4, 1><<<dim3(BT / 128, HID / 128), blk, 0, stream>>>(
        h2, W1T, HID, CC, b1, nullptr, (void*)mid, nullptr, nullptr);
    gemm_tile<128, 64, 4, 1, 2, 4, 0><<<dim3(BT / 128, CC / 64), blk, 0, stream>>>(
        mid, W2T, CC, HID, b2, x1, d_out, nullptr, nullptr);
}